// Round 7
// baseline (2088.256 us; speedup 1.0000x reference)
//
#include <hip/hip_runtime.h>

#define QLEN 256
#define DDIM 64
#define WOUT 32

typedef __bf16 b8v __attribute__((ext_vector_type(8)));
typedef float f4v __attribute__((ext_vector_type(4)));

__device__ __forceinline__ f4v MFMA(b8v a, b8v b, f4v c) {
  return __builtin_amdgcn_mfma_f32_16x16x32_bf16(a, b, c, 0, 0, 0);
}
__device__ __forceinline__ float sigmoidf_(float x) { return 1.0f/(1.0f+__expf(-x)); }
__device__ __forceinline__ float tanhf_(float x)    { return 1.0f - 2.0f/(__expf(2.0f*x)+1.0f); }
__device__ __forceinline__ b8v lda(const __bf16* p, const __bf16* zp, bool pr) {
  return *(const b8v*)(pr ? p : zp);
}

// ---------------- Kernel 1: Kalman scan, ablation-templated ----------------
// VAR=0 full (real) | 1 no-scalar-chain | 2 no-conv-MFMA | 3 no-LDS-A-reads | 4 skeleton
template<int VAR>
__global__ __launch_bounds__(512, 2)
void k_kalman_v(const float* __restrict__ x_in,
                const float* __restrict__ conv_w, const float* __restrict__ conv_b,
                const float* __restrict__ fc1_w,  const float* __restrict__ fc1_b,
                const float* __restrict__ fc2_w,  const float* __restrict__ fc2_b,
                const float* __restrict__ rot1_w, const float* __restrict__ rot1_b,
                const float* __restrict__ rot2_w, const float* __restrict__ rot2_b,
                float* __restrict__ out)
{
  __shared__ __align__(16) __bf16 SMB[11872];
  __shared__ __align__(16) float  SMF[1536];
  const int tid = threadIdx.x;
  const int w  = tid >> 6;
  const int l  = tid & 63;
  const int lr = l & 15;
  const int lg = l >> 4;
  const int wg = blockIdx.x;
  const bool pr8 = (lr < 8);

  __bf16* XPB  = SMB;             // [8][72]
  __bf16* T1   = SMB + 576;       // [8][136]
  __bf16* TC   = SMB + 1664;      // [8][136]
  __bf16* T2   = SMB + 2752;      // [8][136]
  __bf16* FEAT = SMB + 3840;      // [5][8][200]
  const __bf16* ZP = SMB + 11840; // [32] zero line
  float*  XPF  = SMF;             // [8][64]
  float*  XPRI = SMF + 512;       // [8][64]
  float*  INV  = SMF + 1024;      // [8][64]

  for (int i = tid; i < 11872; i += 512) SMB[i] = (__bf16)0.0f;
  for (int i = tid; i < 1536;  i += 512) SMF[i] = 0.0f;

  const int hcol = 16*w + lr;

  b8v r1B[2], f1B[4], f2B[4], cvB[30];
  #pragma unroll
  for (int q = 0; q < 2; ++q)
    #pragma unroll
    for (int j = 0; j < 8; ++j)
      r1B[q][j] = (__bf16)rot1_w[hcol*64 + q*32 + lg*8 + j];
  #pragma unroll
  for (int q = 0; q < 4; ++q)
    #pragma unroll
    for (int j = 0; j < 8; ++j)
      f1B[q][j] = (__bf16)fc1_w[hcol*128 + q*32 + lg*8 + j];
  {
    const int h2 = (w < 4) ? hcol : 0;
    #pragma unroll
    for (int q = 0; q < 4; ++q)
      #pragma unroll
      for (int j = 0; j < 8; ++j)
        f2B[q][j] = (__bf16)fc2_w[h2*128 + q*32 + lg*8 + j];
  }
  #pragma unroll
  for (int c = 0; c < 30; ++c) {
    const int L = c/6, q = c%6;
    #pragma unroll
    for (int j = 0; j < 8; ++j)
      cvB[c][j] = (__bf16)conv_w[hcol*960 + (q*32 + lg*8 + j)*5 + (4-L)];
  }

  const float b_r1 = rot1_b[hcol];
  const float b_f1 = fc1_b[hcol];
  const float b_f2 = fc2_b[(w < 4) ? hcol : 0];
  const float bc   = conv_b[hcol];
  const float r2w00 = rot2_w[l],       r2w01 = rot2_w[64 + l];
  const float r2w10 = rot2_w[128 + l], r2w11 = rot2_w[192 + l];
  const float rb0 = rot2_b[0], rb1 = rot2_b[1];
  const float PI_F = 3.14159274f;

  // runtime-valued synthetic A fragment (V3) — not const-foldable
  b8v synthA;
  {
    __bf16 hv = (__bf16)(0.001f * bc);
    #pragma unroll
    for (int j = 0; j < 8; ++j) synthA[j] = hv;
  }

  const float* xptr = x_in + ((long)(wg*8 + w)*QLEN)*DDIM + l;
  float y_cur = xptr[0];
  float y_prv = y_cur;
  int slot = 0;

  __syncthreads();

  for (int t = 0; t < QLEN; ++t) {
    float y_nxt = (t+1 < QLEN) ? xptr[(t+1)*DDIM] : y_cur;

    // ---- R: rot1 ----
    if constexpr (VAR != 4) {
      b8v a0 = (VAR == 3) ? synthA : lda(&XPB[lr*72      + lg*8], ZP, pr8);
      b8v a1 = (VAR == 3) ? synthA : lda(&XPB[lr*72 + 32 + lg*8], ZP, pr8);
      f4v C = {};
      C = MFMA(a0, r1B[0], C);
      C = MFMA(a1, r1B[1], C);
      if (lg < 2) {
        #pragma unroll
        for (int r = 0; r < 4; ++r) {
          float v = C[r] + b_r1; v = v > 0.f ? v : 0.f;
          T1[(lg*4+r)*136 + hcol] = (__bf16)v;
        }
      }
    }
    __syncthreads();   // B1

    // ---- Y: conv lag1-4 || rot2 scalar chain + rotation + feat ----
    f4v Ca = {}, Cb = {};
    if constexpr (VAR != 2 && VAR != 4) {
      const __bf16* fb1 = FEAT + ((slot-1+5)%5)*1600 + lr*200 + lg*8;
      const __bf16* fb2 = FEAT + ((slot-2+5)%5)*1600 + lr*200 + lg*8;
      const __bf16* fb3 = FEAT + ((slot-3+5)%5)*1600 + lr*200 + lg*8;
      const __bf16* fb4 = FEAT + ((slot-4+5)%5)*1600 + lr*200 + lg*8;
      #pragma unroll
      for (int c = 6; c < 30; ++c) {
        const int L = c/6, q = c%6;
        const __bf16* fb = (L==1) ? fb1 : (L==2) ? fb2 : (L==3) ? fb3 : fb4;
        b8v a = (VAR == 3) ? synthA : lda(&fb[q*32], ZP, pr8);
        if (c & 1) Cb = MFMA(a, cvB[c], Cb); else Ca = MFMA(a, cvB[c], Ca);
      }
    }
    if constexpr (VAR != 4) {
      float cc, ss;
      if constexpr (VAR == 1) {
        cc = 0.01f * bc; ss = 0.01f * b_f1;   // runtime, cheap
      } else {
        float t1a = (float)T1[w*136 + l];
        float t1b = (float)T1[w*136 + 64 + l];
        float acc0 = t1a*r2w00 + t1b*r2w01;
        float acc1 = t1a*r2w10 + t1b*r2w11;
        #pragma unroll
        for (int m = 1; m < 64; m <<= 1) {
          acc0 += __shfl_xor(acc0, m, 64);
          acc1 += __shfl_xor(acc1, m, 64);
        }
        float rho = 1.5f * sigmoidf_(acc0 + rb0);
        float phi = PI_F * tanhf_(acc1 + rb1);
        cc = rho * __cosf(phi);
        ss = rho * __sinf(phi);
      }
      float lo32 = XPF[w*64 + (l & 31)];
      float hi32 = XPF[w*64 + (l & 31) + 32];
      float xpri = (l < 32) ? (lo32*cc - hi32*ss) : (lo32*ss + hi32*cc);
      float innov = y_cur - xpri;
      float diff  = y_cur - y_prv;
      __bf16* fr = FEAT + slot*1600 + w*200;
      fr[l]       = (__bf16)innov;
      fr[128 + l] = (__bf16)diff;
      XPRI[w*64 + l] = xpri;
      INV [w*64 + l] = innov;
    } else {
      XPRI[w*64 + l] = y_cur;   // keep loop live
    }
    __syncthreads();   // B2

    // ---- Z: conv lag0 + relu -> TC ----
    if constexpr (VAR != 4) {
      if constexpr (VAR != 2) {
        const __bf16* fb0 = FEAT + slot*1600 + lr*200 + lg*8;
        #pragma unroll
        for (int c = 0; c < 6; ++c) {
          b8v a = (VAR == 3) ? synthA : lda(&fb0[c*32], ZP, pr8);
          if (c & 1) Cb = MFMA(a, cvB[c], Cb); else Ca = MFMA(a, cvB[c], Ca);
        }
      }
      if (lg < 2) {
        #pragma unroll
        for (int r = 0; r < 4; ++r) {
          float v = Ca[r] + Cb[r] + bc; v = v > 0.f ? v : 0.f;
          TC[(lg*4+r)*136 + hcol] = (__bf16)v;
        }
      }
    }
    __syncthreads();   // B3

    // ---- F1: fc1 ----
    if constexpr (VAR != 4) {
      f4v D0 = {}, D1 = {};
      #pragma unroll
      for (int q = 0; q < 4; ++q) {
        b8v a = (VAR == 3) ? synthA : lda(&TC[lr*136 + q*32 + lg*8], ZP, pr8);
        if (q & 1) D1 = MFMA(a, f1B[q], D1); else D0 = MFMA(a, f1B[q], D0);
      }
      if (lg < 2) {
        #pragma unroll
        for (int r = 0; r < 4; ++r) {
          float v = D0[r] + D1[r] + b_f1; v = v > 0.f ? v : 0.f;
          T2[(lg*4+r)*136 + hcol] = (__bf16)v;
        }
      }
    }
    __syncthreads();   // B4

    const int slot_next = (slot == 4) ? 0 : slot + 1;
    // ---- F2: fc2 -> K -> x_post ----
    if constexpr (VAR != 4) {
      if (w < 4) {
        f4v D0 = {}, D1 = {};
        #pragma unroll
        for (int q = 0; q < 4; ++q) {
          b8v a = (VAR == 3) ? synthA : lda(&T2[lr*136 + q*32 + lg*8], ZP, pr8);
          if (q & 1) D1 = MFMA(a, f2B[q], D1); else D0 = MFMA(a, f2B[q], D0);
        }
        if (lg < 2) {
          #pragma unroll
          for (int r = 0; r < 4; ++r) {
            int e = lg*4 + r;
            float K = sigmoidf_(D0[r] + D1[r] + b_f2);
            float xn = XPRI[e*64 + hcol] + K * INV[e*64 + hcol];
            XPF[e*64 + hcol] = xn;
            XPB[e*72 + hcol] = (__bf16)xn;
            FEAT[slot_next*1600 + e*200 + 64 + hcol] = (__bf16)xn;
          }
        }
      }
    }
    __syncthreads();   // B5

    y_prv = y_cur; y_cur = y_nxt;
    slot = slot_next;
  }

  out[((long)(wg*8 + w)*WOUT)*DDIM + l] = XPF[w*64 + l];
}

// ---------------- Kernel 2: GRU head (unchanged) ----------------
__global__ __launch_bounds__(512, 2)
void k_gru(const float* __restrict__ gru_wih, const float* __restrict__ gru_whh,
           const float* __restrict__ gru_bih, const float* __restrict__ gru_bhh,
           const float* __restrict__ out_w,   const float* __restrict__ out_b,
           float* __restrict__ out)
{
  __shared__ __align__(16) __bf16 CUR[16*72];
  __shared__ __align__(16) __bf16 HB [16*136];
  const int tid = threadIdx.x;
  const int w  = tid >> 6, l = tid & 63, lr = l & 15, lg = l >> 4;
  const int g = blockIdx.x;

  for (int i = tid; i < 16*136; i += 512) HB[i] = (__bf16)0.f;
  for (int i = tid; i < 16*72; i += 512) CUR[i] = (__bf16)0.f;
  __syncthreads();
  for (int i = tid; i < 8*64; i += 512) {
    int e = i >> 6, d = i & 63;
    CUR[e*72 + d] = (__bf16)out[((long)(g*8 + e)*WOUT)*DDIM + d];
  }

  b8v fih[3][2], fhh[3][4], fo[4];
  #pragma unroll
  for (int n3 = 0; n3 < 3; ++n3) {
    int row = 16*(w + 8*n3) + lr;
    #pragma unroll
    for (int q = 0; q < 2; ++q)
      #pragma unroll
      for (int j = 0; j < 8; ++j)
        fih[n3][q][j] = (__bf16)gru_wih[row*64 + q*32 + lg*8 + j];
    #pragma unroll
    for (int q = 0; q < 4; ++q)
      #pragma unroll
      for (int j = 0; j < 8; ++j)
        fhh[n3][q][j] = (__bf16)gru_whh[row*128 + q*32 + lg*8 + j];
  }
  {
    int row = 16*(w & 3) + lr;
    #pragma unroll
    for (int q = 0; q < 4; ++q)
      #pragma unroll
      for (int j = 0; j < 8; ++j)
        fo[q][j] = (__bf16)out_w[row*128 + q*32 + lg*8 + j];
  }
  const int jh = 16*w + lr;
  const float b_ir = gru_bih[jh], b_iz = gru_bih[128+jh], b_in = gru_bih[256+jh];
  const float b_hr = gru_bhh[jh], b_hz = gru_bhh[128+jh], b_hn = gru_bhh[256+jh];
  const float b_o  = out_b[16*(w & 3) + lr];
  const int dcol = 16*(w & 3) + lr;
  __syncthreads();

  for (int s = 0; s < WOUT; ++s) {
    f4v cI[3] = {}, cH[3] = {};
    #pragma unroll
    for (int q = 0; q < 2; ++q) {
      b8v a = *(const b8v*)&CUR[lr*72 + q*32 + lg*8];
      #pragma unroll
      for (int n3 = 0; n3 < 3; ++n3) cI[n3] = MFMA(a, fih[n3][q], cI[n3]);
    }
    #pragma unroll
    for (int q = 0; q < 4; ++q) {
      b8v a = *(const b8v*)&HB[lr*136 + q*32 + lg*8];
      #pragma unroll
      for (int n3 = 0; n3 < 3; ++n3) cH[n3] = MFMA(a, fhh[n3][q], cH[n3]);
    }
    __syncthreads();

    #pragma unroll
    for (int r = 0; r < 4; ++r) {
      int e = lg*4 + r;
      float ir = cI[0][r] + b_ir, iz = cI[1][r] + b_iz, in_ = cI[2][r] + b_in;
      float hr = cH[0][r] + b_hr, hz = cH[1][r] + b_hz, hn  = cH[2][r] + b_hn;
      float rr = sigmoidf_(ir + hr);
      float zz = sigmoidf_(iz + hz);
      float nn = tanhf_(in_ + rr*hn);
      float hold = (float)HB[e*136 + jh];
      float hnew = (1.f - zz)*nn + zz*hold;
      HB[e*136 + jh] = (__bf16)hnew;
    }
    __syncthreads();

    if (w < 4) {
      f4v C0 = {};
      #pragma unroll
      for (int q = 0; q < 4; ++q) {
        b8v a = *(const b8v*)&HB[lr*136 + q*32 + lg*8];
        C0 = MFMA(a, fo[q], C0);
      }
      #pragma unroll
      for (int r = 0; r < 4; ++r) {
        int e = lg*4 + r;
        float cn = (float)CUR[e*72 + dcol] + C0[r] + b_o;
        CUR[e*72 + dcol] = (__bf16)cn;
        if (e < 8)
          out[(((long)(g*8 + e))*WOUT + s)*DDIM + dcol] = cn;
      }
    }
    __syncthreads();
  }
}

extern "C" void kernel_launch(void* const* d_in, const int* in_sizes, int n_in,
                              void* d_out, int out_size, void* d_ws, size_t ws_size,
                              hipStream_t stream) {
  (void)in_sizes; (void)n_in; (void)d_ws; (void)ws_size; (void)out_size;
  const float* x_in   = (const float*)d_in[0];
  const float* conv_w = (const float*)d_in[2];
  const float* conv_b = (const float*)d_in[3];
  const float* fc1_w  = (const float*)d_in[4];
  const float* fc1_b  = (const float*)d_in[5];
  const float* fc2_w  = (const float*)d_in[6];
  const float* fc2_b  = (const float*)d_in[7];
  const float* rot1_w = (const float*)d_in[8];
  const float* rot1_b = (const float*)d_in[9];
  const float* rot2_w = (const float*)d_in[10];
  const float* rot2_b = (const float*)d_in[11];
  const float* gwih   = (const float*)d_in[12];
  const float* gwhh   = (const float*)d_in[13];
  const float* gbih   = (const float*)d_in[14];
  const float* gbhh   = (const float*)d_in[15];
  const float* ow     = (const float*)d_in[16];
  const float* ob     = (const float*)d_in[17];
  float* out = (float*)d_out;

  // diagnostic variants (outputs overwritten by the real pair below)
  k_kalman_v<4><<<256, 512, 0, stream>>>(x_in, conv_w, conv_b, fc1_w, fc1_b,
                                         fc2_w, fc2_b, rot1_w, rot1_b, rot2_w, rot2_b, out);
  k_kalman_v<3><<<256, 512, 0, stream>>>(x_in, conv_w, conv_b, fc1_w, fc1_b,
                                         fc2_w, fc2_b, rot1_w, rot1_b, rot2_w, rot2_b, out);
  k_kalman_v<2><<<256, 512, 0, stream>>>(x_in, conv_w, conv_b, fc1_w, fc1_b,
                                         fc2_w, fc2_b, rot1_w, rot1_b, rot2_w, rot2_b, out);
  k_kalman_v<1><<<256, 512, 0, stream>>>(x_in, conv_w, conv_b, fc1_w, fc1_b,
                                         fc2_w, fc2_b, rot1_w, rot1_b, rot2_w, rot2_b, out);
  // real computation
  k_kalman_v<0><<<256, 512, 0, stream>>>(x_in, conv_w, conv_b, fc1_w, fc1_b,
                                         fc2_w, fc2_b, rot1_w, rot1_b, rot2_w, rot2_b, out);
  k_gru<<<256, 512, 0, stream>>>(gwih, gwhh, gbih, gbhh, ow, ob, out);
}

// Round 8
// 679.440 us; speedup vs baseline: 3.0735x; 3.0735x over previous
//
#include <hip/hip_runtime.h>

#define QLEN 256
#define DDIM 64
#define WOUT 32

typedef __bf16 b8v __attribute__((ext_vector_type(8)));
typedef float f4v __attribute__((ext_vector_type(4)));

__device__ __forceinline__ f4v MFMA(b8v a, b8v b, f4v c) {
  return __builtin_amdgcn_mfma_f32_16x16x32_bf16(a, b, c, 0, 0, 0);
}
__device__ __forceinline__ float sigmoidf_(float x) { return 1.0f/(1.0f+__expf(-x)); }
__device__ __forceinline__ float tanhf_(float x)    { return 1.0f - 2.0f/(__expf(2.0f*x)+1.0f); }

// ---------------- Kernel 1: Kalman scan (256 steps) ----------------
// 256 WGs x 512 threads (8 waves); WG owns 8 batch rows (M=16 tile, rows 8..15
// garbage-but-row-contained). N-split conv: wave w owns output cols 16w..16w+15
// of every GEMM, all 30 K-chunks in registers. 5 barriers/step.
// Y phase: 26 chunks (lags1-4 + lag0-xpv, all available pre-feat) overlapped
// with the rot2 scalar chain; Z phase: 4 lag0 innov/diff chunks only.
// 6 conv accumulators cap the same-accumulator MFMA dependency depth at ~5.
__global__ __launch_bounds__(512, 2)
void k_kalman(const float* __restrict__ x_in,
              const float* __restrict__ conv_w, const float* __restrict__ conv_b,
              const float* __restrict__ fc1_w,  const float* __restrict__ fc1_b,
              const float* __restrict__ fc2_w,  const float* __restrict__ fc2_b,
              const float* __restrict__ rot1_w, const float* __restrict__ rot1_b,
              const float* __restrict__ rot2_w, const float* __restrict__ rot2_b,
              float* __restrict__ out)
{
  __shared__ __align__(16) __bf16 SMB[11872];
  __shared__ __align__(16) float  SMF[1536];
  const int tid = threadIdx.x;
  const int w  = tid >> 6;      // wave 0..7 (owns output N-tile w of every GEMM)
  const int l  = tid & 63;
  const int lr = l & 15;
  const int lg = l >> 4;
  const int wg = blockIdx.x;

  __bf16* XPB  = SMB;            // [8][72]   x_post bf16 (A-operand for rot1)
  __bf16* T1   = SMB + 576;      // [8][136]  relu(rot1)
  __bf16* TC   = SMB + 1664;     // [8][136]  relu(conv)
  __bf16* T2   = SMB + 2752;     // [8][136]  relu(fc1)
  __bf16* FEAT = SMB + 3840;     // [5][8][200] feat ring (innov|xpv|diff)
  float*  XPF  = SMF;            // [8][64] x_post fp32 master
  float*  XPRI = SMF + 512;      // [8][64]
  float*  INV  = SMF + 1024;     // [8][64]

  for (int i = tid; i < 11872; i += 512) SMB[i] = (__bf16)0.0f;
  for (int i = tid; i < 1536;  i += 512) SMF[i] = 0.0f;

  const int hcol = 16*w + lr;    // this wave's output column in every GEMM

  // ---- register/AGPR-resident B fragments (weights, bf16) ----
  b8v r1B[2], f1B[4], f2B[4], cvB[30];
  #pragma unroll
  for (int q = 0; q < 2; ++q)
    #pragma unroll
    for (int j = 0; j < 8; ++j)
      r1B[q][j] = (__bf16)rot1_w[hcol*64 + q*32 + lg*8 + j];
  #pragma unroll
  for (int q = 0; q < 4; ++q)
    #pragma unroll
    for (int j = 0; j < 8; ++j)
      f1B[q][j] = (__bf16)fc1_w[hcol*128 + q*32 + lg*8 + j];
  {
    const int h2 = (w < 4) ? hcol : 0;   // fc2_w has 64 rows
    #pragma unroll
    for (int q = 0; q < 4; ++q)
      #pragma unroll
      for (int j = 0; j < 8; ++j)
        f2B[q][j] = (__bf16)fc2_w[h2*128 + q*32 + lg*8 + j];
  }
  #pragma unroll
  for (int c = 0; c < 30; ++c) {
    const int L = c/6, q = c%6;
    #pragma unroll
    for (int j = 0; j < 8; ++j)
      cvB[c][j] = (__bf16)conv_w[hcol*960 + (q*32 + lg*8 + j)*5 + (4-L)];
  }

  const float b_r1 = rot1_b[hcol];
  const float b_f1 = fc1_b[hcol];
  const float b_f2 = fc2_b[(w < 4) ? hcol : 0];
  const float bc   = conv_b[hcol];
  const float r2w00 = rot2_w[l],       r2w01 = rot2_w[64 + l];
  const float r2w10 = rot2_w[128 + l], r2w11 = rot2_w[192 + l];
  const float rb0 = rot2_b[0], rb1 = rot2_b[1];
  const float PI_F = 3.14159274f;

  const float* xptr = x_in + ((long)(wg*8 + w)*QLEN)*DDIM + l;
  float y_cur = xptr[0];
  float y_prv = y_cur;
  int slot = 0;

  // Y-phase chunk order: lag0-xpv first (c=2,3), then lags 1-4
  constexpr int YC[26] = {2,3, 6,7,8,9,10,11, 12,13,14,15,16,17,
                          18,19,20,21,22,23, 24,25,26,27,28,29};

  __syncthreads();

  for (int t = 0; t < QLEN; ++t) {
    // ---- R: t1 = relu(x_post @ rot1_w^T + b), tile w ----
    {
      b8v a0 = *(const b8v*)&XPB[lr*72      + lg*8];
      b8v a1 = *(const b8v*)&XPB[lr*72 + 32 + lg*8];
      f4v C = {};
      C = MFMA(a0, r1B[0], C);
      C = MFMA(a1, r1B[1], C);
      if (lg < 2) {
        #pragma unroll
        for (int r = 0; r < 4; ++r) {
          float v = C[r] + b_r1; v = v > 0.f ? v : 0.f;
          T1[(lg*4+r)*136 + hcol] = (__bf16)v;
        }
      }
    }
    __syncthreads();   // B1: T1 ready

    // ---- Y: conv 26 pre-feat chunks (6 accums) || rot2 + rotation + feat ----
    float y_nxt = (t+1 < QLEN) ? xptr[(t+1)*DDIM] : y_cur;
    f4v A0 = {}, A1 = {}, A2 = {}, A3 = {}, A4 = {}, A5 = {};
    {
      const __bf16* fb0 = FEAT + slot*1600                + lr*200 + lg*8;
      const __bf16* fb1 = FEAT + ((slot-1+5)%5)*1600 + lr*200 + lg*8;
      const __bf16* fb2 = FEAT + ((slot-2+5)%5)*1600 + lr*200 + lg*8;
      const __bf16* fb3 = FEAT + ((slot-3+5)%5)*1600 + lr*200 + lg*8;
      const __bf16* fb4 = FEAT + ((slot-4+5)%5)*1600 + lr*200 + lg*8;
      #pragma unroll
      for (int i = 0; i < 26; ++i) {
        const int c = YC[i], L = c/6, q = c%6;
        const __bf16* fb = (L==0) ? fb0 : (L==1) ? fb1 : (L==2) ? fb2
                         : (L==3) ? fb3 : fb4;
        b8v a = *(const b8v*)&fb[q*32];
        const int s6 = i % 6;
        if      (s6 == 0) A0 = MFMA(a, cvB[c], A0);
        else if (s6 == 1) A1 = MFMA(a, cvB[c], A1);
        else if (s6 == 2) A2 = MFMA(a, cvB[c], A2);
        else if (s6 == 3) A3 = MFMA(a, cvB[c], A3);
        else if (s6 == 4) A4 = MFMA(a, cvB[c], A4);
        else              A5 = MFMA(a, cvB[c], A5);
      }
    }
    {
      float t1a = (float)T1[w*136 + l];
      float t1b = (float)T1[w*136 + 64 + l];
      float acc0 = t1a*r2w00 + t1b*r2w01;
      float acc1 = t1a*r2w10 + t1b*r2w11;
      #pragma unroll
      for (int m = 1; m < 64; m <<= 1) {
        acc0 += __shfl_xor(acc0, m, 64);
        acc1 += __shfl_xor(acc1, m, 64);
      }
      float rho = 1.5f * sigmoidf_(acc0 + rb0);
      float phi = PI_F * tanhf_(acc1 + rb1);
      float cc = rho * __cosf(phi);
      float ss = rho * __sinf(phi);
      float lo32 = XPF[w*64 + (l & 31)];
      float hi32 = XPF[w*64 + (l & 31) + 32];
      float xpri = (l < 32) ? (lo32*cc - hi32*ss) : (lo32*ss + hi32*cc);
      float innov = y_cur - xpri;
      float diff  = y_cur - y_prv;
      __bf16* fr = FEAT + slot*1600 + w*200;
      fr[l]       = (__bf16)innov;
      fr[128 + l] = (__bf16)diff;     // xpv slice [64+l] prewritten by prev F2
      XPRI[w*64 + l] = xpri;
      INV [w*64 + l] = innov;
    }
    __syncthreads();   // B2: feat(t) ready

    // ---- Z: conv lag0 innov/diff chunks {0,1,4,5} + bias + relu -> TC ----
    {
      const __bf16* fb0 = FEAT + slot*1600 + lr*200 + lg*8;
      b8v a;
      a = *(const b8v*)&fb0[0*32];  A0 = MFMA(a, cvB[0], A0);
      a = *(const b8v*)&fb0[1*32];  A1 = MFMA(a, cvB[1], A1);
      a = *(const b8v*)&fb0[4*32];  A2 = MFMA(a, cvB[4], A2);
      a = *(const b8v*)&fb0[5*32];  A3 = MFMA(a, cvB[5], A3);
      if (lg < 2) {
        #pragma unroll
        for (int r = 0; r < 4; ++r) {
          float v = A0[r] + A1[r] + A2[r] + A3[r] + A4[r] + A5[r] + bc;
          v = v > 0.f ? v : 0.f;
          TC[(lg*4+r)*136 + hcol] = (__bf16)v;
        }
      }
    }
    __syncthreads();   // B3: TC ready

    // ---- F1: fc1 tile w ----
    {
      f4v D0 = {}, D1 = {};
      #pragma unroll
      for (int q = 0; q < 4; ++q) {
        b8v a = *(const b8v*)&TC[lr*136 + q*32 + lg*8];
        if (q & 1) D1 = MFMA(a, f1B[q], D1); else D0 = MFMA(a, f1B[q], D0);
      }
      if (lg < 2) {
        #pragma unroll
        for (int r = 0; r < 4; ++r) {
          float v = D0[r] + D1[r] + b_f1; v = v > 0.f ? v : 0.f;
          T2[(lg*4+r)*136 + hcol] = (__bf16)v;
        }
      }
    }
    __syncthreads();   // B4: T2 ready

    const int slot_next = (slot == 4) ? 0 : slot + 1;
    // ---- F2: K = sigmoid(fc2), x_post update + next-step xpv prewrite (waves 0..3) ----
    if (w < 4) {
      f4v D0 = {}, D1 = {};
      #pragma unroll
      for (int q = 0; q < 4; ++q) {
        b8v a = *(const b8v*)&T2[lr*136 + q*32 + lg*8];
        if (q & 1) D1 = MFMA(a, f2B[q], D1); else D0 = MFMA(a, f2B[q], D0);
      }
      if (lg < 2) {
        #pragma unroll
        for (int r = 0; r < 4; ++r) {
          int e = lg*4 + r;
          float K = sigmoidf_(D0[r] + D1[r] + b_f2);
          float xn = XPRI[e*64 + hcol] + K * INV[e*64 + hcol];
          XPF[e*64 + hcol] = xn;
          XPB[e*72 + hcol] = (__bf16)xn;
          FEAT[slot_next*1600 + e*200 + 64 + hcol] = (__bf16)xn;  // xpv of feat(t+1)
        }
      }
    }
    __syncthreads();   // B5: x_post ready for next rot1

    y_prv = y_cur; y_cur = y_nxt;
    slot = slot_next;
  }

  // stash fp32 x_post into out[b][0][:] (GRU kernel reads then overwrites)
  out[((long)(wg*8 + w)*WOUT)*DDIM + l] = XPF[w*64 + l];
}

// ---------------- Kernel 2: GRU head (32 steps) ----------------
// 256 WGs x 512 threads; each WG owns 8 batch rows (M=16 tile, rows 8..15 isolated).
__global__ __launch_bounds__(512, 2)
void k_gru(const float* __restrict__ gru_wih, const float* __restrict__ gru_whh,
           const float* __restrict__ gru_bih, const float* __restrict__ gru_bhh,
           const float* __restrict__ out_w,   const float* __restrict__ out_b,
           float* __restrict__ out)
{
  __shared__ __align__(16) __bf16 CUR[16*72];
  __shared__ __align__(16) __bf16 HB [16*136];
  const int tid = threadIdx.x;
  const int w  = tid >> 6, l = tid & 63, lr = l & 15, lg = l >> 4;
  const int g = blockIdx.x;

  for (int i = tid; i < 16*136; i += 512) HB[i] = (__bf16)0.f;
  for (int i = tid; i < 16*72; i += 512) CUR[i] = (__bf16)0.f;
  __syncthreads();
  for (int i = tid; i < 8*64; i += 512) {
    int e = i >> 6, d = i & 63;
    CUR[e*72 + d] = (__bf16)out[((long)(g*8 + e)*WOUT)*DDIM + d];
  }

  b8v fih[3][2], fhh[3][4], fo[4];
  #pragma unroll
  for (int n3 = 0; n3 < 3; ++n3) {
    int row = 16*(w + 8*n3) + lr;
    #pragma unroll
    for (int q = 0; q < 2; ++q)
      #pragma unroll
      for (int j = 0; j < 8; ++j)
        fih[n3][q][j] = (__bf16)gru_wih[row*64 + q*32 + lg*8 + j];
    #pragma unroll
    for (int q = 0; q < 4; ++q)
      #pragma unroll
      for (int j = 0; j < 8; ++j)
        fhh[n3][q][j] = (__bf16)gru_whh[row*128 + q*32 + lg*8 + j];
  }
  {
    int row = 16*(w & 3) + lr;
    #pragma unroll
    for (int q = 0; q < 4; ++q)
      #pragma unroll
      for (int j = 0; j < 8; ++j)
        fo[q][j] = (__bf16)out_w[row*128 + q*32 + lg*8 + j];
  }
  const int jh = 16*w + lr;
  const float b_ir = gru_bih[jh], b_iz = gru_bih[128+jh], b_in = gru_bih[256+jh];
  const float b_hr = gru_bhh[jh], b_hz = gru_bhh[128+jh], b_hn = gru_bhh[256+jh];
  const float b_o  = out_b[16*(w & 3) + lr];
  const int dcol = 16*(w & 3) + lr;
  __syncthreads();

  for (int s = 0; s < WOUT; ++s) {
    f4v cI[3] = {}, cH[3] = {};
    #pragma unroll
    for (int q = 0; q < 2; ++q) {
      b8v a = *(const b8v*)&CUR[lr*72 + q*32 + lg*8];
      #pragma unroll
      for (int n3 = 0; n3 < 3; ++n3) cI[n3] = MFMA(a, fih[n3][q], cI[n3]);
    }
    #pragma unroll
    for (int q = 0; q < 4; ++q) {
      b8v a = *(const b8v*)&HB[lr*136 + q*32 + lg*8];
      #pragma unroll
      for (int n3 = 0; n3 < 3; ++n3) cH[n3] = MFMA(a, fhh[n3][q], cH[n3]);
    }
    __syncthreads();

    #pragma unroll
    for (int r = 0; r < 4; ++r) {
      int e = lg*4 + r;
      float ir = cI[0][r] + b_ir, iz = cI[1][r] + b_iz, in_ = cI[2][r] + b_in;
      float hr = cH[0][r] + b_hr, hz = cH[1][r] + b_hz, hn  = cH[2][r] + b_hn;
      float rr = sigmoidf_(ir + hr);
      float zz = sigmoidf_(iz + hz);
      float nn = tanhf_(in_ + rr*hn);
      float hold = (float)HB[e*136 + jh];
      float hnew = (1.f - zz)*nn + zz*hold;
      HB[e*136 + jh] = (__bf16)hnew;
    }
    __syncthreads();

    if (w < 4) {
      f4v C0 = {};
      #pragma unroll
      for (int q = 0; q < 4; ++q) {
        b8v a = *(const b8v*)&HB[lr*136 + q*32 + lg*8];
        C0 = MFMA(a, fo[q], C0);
      }
      #pragma unroll
      for (int r = 0; r < 4; ++r) {
        int e = lg*4 + r;
        float cn = (float)CUR[e*72 + dcol] + C0[r] + b_o;
        CUR[e*72 + dcol] = (__bf16)cn;
        if (e < 8)
          out[(((long)(g*8 + e))*WOUT + s)*DDIM + dcol] = cn;
      }
    }
    __syncthreads();
  }
}

extern "C" void kernel_launch(void* const* d_in, const int* in_sizes, int n_in,
                              void* d_out, int out_size, void* d_ws, size_t ws_size,
                              hipStream_t stream) {
  (void)in_sizes; (void)n_in; (void)d_ws; (void)ws_size; (void)out_size;
  const float* x_in   = (const float*)d_in[0];
  const float* conv_w = (const float*)d_in[2];
  const float* conv_b = (const float*)d_in[3];
  const float* fc1_w  = (const float*)d_in[4];
  const float* fc1_b  = (const float*)d_in[5];
  const float* fc2_w  = (const float*)d_in[6];
  const float* fc2_b  = (const float*)d_in[7];
  const float* rot1_w = (const float*)d_in[8];
  const float* rot1_b = (const float*)d_in[9];
  const float* rot2_w = (const float*)d_in[10];
  const float* rot2_b = (const float*)d_in[11];
  const float* gwih   = (const float*)d_in[12];
  const float* gwhh   = (const float*)d_in[13];
  const float* gbih   = (const float*)d_in[14];
  const float* gbhh   = (const float*)d_in[15];
  const float* ow     = (const float*)d_in[16];
  const float* ob     = (const float*)d_in[17];
  float* out = (float*)d_out;

  k_kalman<<<256, 512, 0, stream>>>(x_in, conv_w, conv_b, fc1_w, fc1_b,
                                    fc2_w, fc2_b, rot1_w, rot1_b,
                                    rot2_w, rot2_b, out);
  k_gru<<<256, 512, 0, stream>>>(gwih, gwhh, gbih, gbhh, ow, ob, out);
}